// Round 1
// baseline (1312.037 us; speedup 1.0000x reference)
//
#include <hip/hip_runtime.h>

#define G_NUM 256
#define D_DIM 128

// ---------------- kernel 0: zero the workspace accumulators ----------------
__global__ void zero_ws_kernel(float* __restrict__ ws, int n) {
    int i = blockIdx.x * blockDim.x + threadIdx.x;
    if (i < n) ws[i] = 0.0f;
}

// ---------------- kernel 1: segmented sum + count (batch is sorted) --------
// Layout: 256 threads/block = 8 row-groups of 32 lanes; lane handles one
// float4 (16B) of the 512B row -> fully coalesced. Each thread accumulates in
// a register float4 while the segment id is unchanged; flushes via atomicAdd
// only at segment boundaries (~1.1 flushes/thread with 256 segments of ~7.8k
// rows and ~977-row block chunks).
__global__ __launch_bounds__(256) void seg_sum_kernel(
    const float4* __restrict__ x4, const int* __restrict__ batch,
    float* __restrict__ sums, unsigned int* __restrict__ counts,
    int n_rows, int rows_per_block)
{
    const int lane = threadIdx.x & 31;   // float4 slot within the row
    const int sub  = threadIdx.x >> 5;   // which of 8 concurrent rows
    const int row_start = blockIdx.x * rows_per_block;
    const int row_end   = min(n_rows, row_start + rows_per_block);

    int g_cur = -1;
    float4 acc = make_float4(0.f, 0.f, 0.f, 0.f);
    unsigned int cnt = 0;

    for (int r = row_start + sub; r < row_end; r += 8) {
        const int b = batch[r];
        if (b != g_cur) {
            if (g_cur >= 0) {
                float* dst = sums + (size_t)g_cur * D_DIM + lane * 4;
                atomicAdd(dst + 0, acc.x);
                atomicAdd(dst + 1, acc.y);
                atomicAdd(dst + 2, acc.z);
                atomicAdd(dst + 3, acc.w);
                if (lane == 0) atomicAdd(&counts[g_cur], cnt);
            }
            g_cur = b;
            acc = make_float4(0.f, 0.f, 0.f, 0.f);
            cnt = 0;
        }
        const float4 v = x4[(size_t)r * (D_DIM / 4) + lane];
        acc.x += v.x; acc.y += v.y; acc.z += v.z; acc.w += v.w;
        ++cnt;
    }
    if (g_cur >= 0) {
        float* dst = sums + (size_t)g_cur * D_DIM + lane * 4;
        atomicAdd(dst + 0, acc.x);
        atomicAdd(dst + 1, acc.y);
        atomicAdd(dst + 2, acc.z);
        atomicAdd(dst + 3, acc.w);
        if (lane == 0) atomicAdd(&counts[g_cur], cnt);
    }
}

// ---------------- kernel 2: mean + MLP head --------------------------------
// One wave (64 threads) per graph. mean row staged in LDS (broadcast reads,
// conflict-free); thread j computes h[j] = relu(mean . W1[:,j] + b1[j]) with
// coalesced W1 reads (W1 row-major [128,64]); then 64-lane shuffle reduction
// of h[j]*W2[j].
__global__ __launch_bounds__(64) void mlp_kernel(
    const float* __restrict__ sums, const unsigned int* __restrict__ counts,
    const float* __restrict__ W1, const float* __restrict__ b1,
    const float* __restrict__ W2, const float* __restrict__ b2,
    float* __restrict__ out)
{
    const int g = blockIdx.x;
    const int j = threadIdx.x;   // 0..63
    __shared__ float mean_s[D_DIM];

    const float c = (float)counts[g];
    mean_s[j]      = sums[(size_t)g * D_DIM + j]      / c;
    mean_s[j + 64] = sums[(size_t)g * D_DIM + j + 64] / c;
    __syncthreads();

    float acc = b1[j];
#pragma unroll 8
    for (int k = 0; k < D_DIM; ++k)
        acc += mean_s[k] * W1[k * (D_DIM / 2) + j];

    float p = fmaxf(acc, 0.0f) * W2[j];

    // 64-lane wave reduction
    for (int off = 32; off > 0; off >>= 1)
        p += __shfl_down(p, off, 64);

    if (j == 0) out[g] = p + b2[0];
}

// ---------------- launch ---------------------------------------------------
extern "C" void kernel_launch(void* const* d_in, const int* in_sizes, int n_in,
                              void* d_out, int out_size, void* d_ws, size_t ws_size,
                              hipStream_t stream) {
    const float* x     = (const float*)d_in[0];
    const int*   batch = (const int*)d_in[1];
    const float* W1    = (const float*)d_in[2];
    const float* b1    = (const float*)d_in[3];
    const float* W2    = (const float*)d_in[4];
    const float* b2    = (const float*)d_in[5];
    float*       out   = (float*)d_out;

    const int n_rows = in_sizes[1];   // N (batch index array length)

    float*        sums   = (float*)d_ws;
    unsigned int* counts = (unsigned int*)((char*)d_ws + (size_t)G_NUM * D_DIM * sizeof(float));

    // zero sums + counts (contiguous, both zero-bit-pattern)
    const int zero_n = G_NUM * D_DIM + G_NUM;
    zero_ws_kernel<<<(zero_n + 255) / 256, 256, 0, stream>>>((float*)d_ws, zero_n);

    const int nblocks = 2048;
    const int rows_per_block = (n_rows + nblocks - 1) / nblocks;
    seg_sum_kernel<<<nblocks, 256, 0, stream>>>(
        (const float4*)x, batch, sums, counts, n_rows, rows_per_block);

    mlp_kernel<<<G_NUM, 64, 0, stream>>>(sums, counts, W1, b1, W2, b2, out);
}